// Round 2
// baseline (946.152 us; speedup 1.0000x reference)
//
#include <hip/hip_runtime.h>

constexpr int LDIM  = 128;
constexpr int NNODE = 20000;
constexpr int EM_N  = 100000;
constexpr int EW_N  = 25000;
constexpr int NSTEP = 6;

typedef short bf16x8 __attribute__((ext_vector_type(8)));
typedef float f32x4  __attribute__((ext_vector_type(4)));

struct MlpParams {
  const float* x;       // node features (gather source / node input)
  const float* attrIn;  // residual input (edge attr or x)
  float*       attrOut; // residual output
  const int*   src;     // edge senders
  const int*   dst;     // edge receivers
  float*       sum1;    // edge: scatter target; node: mesh sum (zeroed after read)
  float*       sum2;    // node: world sum (zeroed after read)
  const float* inv1;    // node: 1/max(deg_mesh,1)
  const float* inv2;    // node: 1/max(deg_world,1)
  const short* W1H;     // bf16 hi [128][384]
  const short* W1L;     // bf16 lo [128][384]
  const short* W2H;     // bf16 hi [128][128]
  const short* W2L;     // bf16 lo [128][128]
  const float* b1;
  const float* b2;
  const float* gam;
  const float* bet;
  int nRows;
};

__device__ __forceinline__ short f2b(float f) {
  unsigned int u = __float_as_uint(f);
  u = (u + 0x7fffu + ((u >> 16) & 1u)) >> 16;
  return (short)u;
}
__device__ __forceinline__ float b2f(short s) {
  return __uint_as_float(((unsigned int)(unsigned short)s) << 16);
}

// 128 rows/block, 256 threads (4 waves, 2x2), wave tile 64x64, 16x16x32 bf16 MFMA.
// Weights applied as hi+lo bf16 pairs (fp32-accurate weights); LN epilogue in f32
// straight from accumulators.
template<bool IS_EDGE>
__launch_bounds__(256, 2)
__global__ void mlp_kernel(MlpParams pmA, MlpParams pmB, int blocksA) {
  const bool isA = (int)blockIdx.x < blocksA;
  const MlpParams P = isA ? pmA : pmB;
  const int bid  = isA ? (int)blockIdx.x : (int)blockIdx.x - blocksA;
  const int row0 = bid * 128;

  __shared__ __align__(16) short Abuf[128][40];   // pad->stride 80B: aligned + 2-way banks
  __shared__ __align__(16) short Bhi[128][40];
  __shared__ __align__(16) short Blo[128][40];
  __shared__ __align__(16) short Hbuf[128][136];  // stride 272B: aligned + 2-way banks
  __shared__ float b1s[128], b2s[128], gs[128], bes[128];
  __shared__ int   idxa[128], idxb[128];
  __shared__ float inv1s[128], inv2s[128];
  __shared__ float sumL[2][128], sqL[2][128];
  __shared__ float muL[128], rsL[128];

  const int t = threadIdx.x;

  // prologue staging of per-block small arrays
  if (t < 128) {
    b1s[t] = P.b1[t];
    gs[t]  = P.gam[t];
    if (IS_EDGE) {
      int r = row0 + t;
      idxa[t] = (r < P.nRows) ? P.src[r] : 0;
    } else {
      int r = min(row0 + t, P.nRows - 1);
      inv1s[t] = P.inv1[r];
    }
  } else {
    int t2 = t - 128;
    b2s[t2] = P.b2[t2];
    bes[t2] = P.bet[t2];
    if (IS_EDGE) {
      int r = row0 + t2;
      idxb[t2] = (r < P.nRows) ? P.dst[r] : 0;
    } else {
      int r = min(row0 + t2, P.nRows - 1);
      inv2s[t2] = P.inv2[r];
    }
  }

  const int l   = t & 63;
  const int wid = t >> 6;
  const int wr  = wid >> 1, wcc = wid & 1;
  const int lr  = l & 15,  lg  = l >> 4;

  const int  srow  = t >> 1, sh = t & 1;   // staging row assignment
  const int  sgRow = row0 + srow;
  const bool sval  = sgRow < P.nRows;

  f32x4 acc[4][4];
#pragma unroll
  for (int i = 0; i < 4; ++i)
#pragma unroll
    for (int j = 0; j < 4; ++j) acc[i][j] = f32x4{0.f, 0.f, 0.f, 0.f};

  // ---------------- phase 1: H = relu(A @ W1 + b1), K = 384 ----------------
  for (int kc = 0; kc < 12; ++kc) {
    __syncthreads();
    { // stage A chunk [128 rows][32 k] with gather + f32->bf16 (2 threads/row)
      const int seg = kc >> 2, part = kc & 3;
      float v[16];
      if (sval) {
        const float* sbase;
        float sc = 1.0f;
        if (IS_EDGE) {
          sbase = (seg == 0) ? P.x + (size_t)idxa[srow] * LDIM
                : (seg == 1) ? P.x + (size_t)idxb[srow] * LDIM
                             : P.attrIn + (size_t)sgRow * LDIM;
        } else {
          if (seg == 0)      { sbase = P.x    + (size_t)sgRow * LDIM; }
          else if (seg == 1) { sbase = P.sum1 + (size_t)sgRow * LDIM; sc = inv1s[srow]; }
          else               { sbase = P.sum2 + (size_t)sgRow * LDIM; sc = inv2s[srow]; }
        }
        const float4* s4 = (const float4*)(sbase + part * 32 + sh * 16);
        float4 a0 = s4[0], a1 = s4[1], a2 = s4[2], a3 = s4[3];
        v[0]=a0.x;  v[1]=a0.y;  v[2]=a0.z;  v[3]=a0.w;
        v[4]=a1.x;  v[5]=a1.y;  v[6]=a1.z;  v[7]=a1.w;
        v[8]=a2.x;  v[9]=a2.y;  v[10]=a2.z; v[11]=a2.w;
        v[12]=a3.x; v[13]=a3.y; v[14]=a3.z; v[15]=a3.w;
        if (!IS_EDGE && seg != 0) {
#pragma unroll
          for (int e = 0; e < 16; ++e) v[e] *= sc;
          // zero-after-read: this element set is read exactly once per step
          float4 z = {0.f, 0.f, 0.f, 0.f};
          float4* zp = (float4*)(sbase + part * 32 + sh * 16);
          zp[0] = z; zp[1] = z; zp[2] = z; zp[3] = z;
        }
      } else {
#pragma unroll
        for (int e = 0; e < 16; ++e) v[e] = 0.f;
      }
      bf16x8 o0, o1;
#pragma unroll
      for (int e = 0; e < 8; ++e) { o0[e] = f2b(v[e]); o1[e] = f2b(v[8 + e]); }
      *(bf16x8*)&Abuf[srow][sh * 16]     = o0;
      *(bf16x8*)&Abuf[srow][sh * 16 + 8] = o1;
    }
    { // stage B chunk (hi+lo): W1T[n][384], cols kc*32..+31
      const size_t off = (size_t)srow * 384 + kc * 32 + sh * 16;
      const short* wh = P.W1H + off;
      const short* wl = P.W1L + off;
      *(bf16x8*)&Bhi[srow][sh * 16]     = *(const bf16x8*)wh;
      *(bf16x8*)&Bhi[srow][sh * 16 + 8] = *(const bf16x8*)(wh + 8);
      *(bf16x8*)&Blo[srow][sh * 16]     = *(const bf16x8*)wl;
      *(bf16x8*)&Blo[srow][sh * 16 + 8] = *(const bf16x8*)(wl + 8);
    }
    __syncthreads();
    bf16x8 av[4], bh[4], bl[4];
#pragma unroll
    for (int rt = 0; rt < 4; ++rt) av[rt] = *(const bf16x8*)&Abuf[wr * 64 + rt * 16 + lr][lg * 8];
#pragma unroll
    for (int ct = 0; ct < 4; ++ct) {
      bh[ct] = *(const bf16x8*)&Bhi[wcc * 64 + ct * 16 + lr][lg * 8];
      bl[ct] = *(const bf16x8*)&Blo[wcc * 64 + ct * 16 + lr][lg * 8];
    }
#pragma unroll
    for (int rt = 0; rt < 4; ++rt)
#pragma unroll
      for (int ct = 0; ct < 4; ++ct) {
        acc[rt][ct] = __builtin_amdgcn_mfma_f32_16x16x32_bf16(av[rt], bl[ct], acc[rt][ct], 0, 0, 0);
        acc[rt][ct] = __builtin_amdgcn_mfma_f32_16x16x32_bf16(av[rt], bh[ct], acc[rt][ct], 0, 0, 0);
      }
  }

  // write H = relu(acc + b1) to LDS as bf16
#pragma unroll
  for (int rt = 0; rt < 4; ++rt)
#pragma unroll
    for (int ct = 0; ct < 4; ++ct) {
      const int cc = wcc * 64 + ct * 16 + lr;
      const float bb = b1s[cc];
#pragma unroll
      for (int q = 0; q < 4; ++q) {
        const int rr = wr * 64 + rt * 16 + lg * 4 + q;
        Hbuf[rr][cc] = f2b(fmaxf(acc[rt][ct][q] + bb, 0.f));
      }
    }

  // ---------------- phase 2: OUT = H @ W2 + b2, K = 128 ----------------
  f32x4 acc2[4][4];
#pragma unroll
  for (int i = 0; i < 4; ++i)
#pragma unroll
    for (int j = 0; j < 4; ++j) acc2[i][j] = f32x4{0.f, 0.f, 0.f, 0.f};

  for (int kc = 0; kc < 4; ++kc) {
    __syncthreads();   // first iter also publishes Hbuf writes
    {
      const size_t off = (size_t)srow * 128 + kc * 32 + sh * 16;
      const short* wh = P.W2H + off;
      const short* wl = P.W2L + off;
      *(bf16x8*)&Bhi[srow][sh * 16]     = *(const bf16x8*)wh;
      *(bf16x8*)&Bhi[srow][sh * 16 + 8] = *(const bf16x8*)(wh + 8);
      *(bf16x8*)&Blo[srow][sh * 16]     = *(const bf16x8*)wl;
      *(bf16x8*)&Blo[srow][sh * 16 + 8] = *(const bf16x8*)(wl + 8);
    }
    __syncthreads();
    bf16x8 av2[4], bh2[4], bl2[4];
#pragma unroll
    for (int rt = 0; rt < 4; ++rt) av2[rt] = *(const bf16x8*)&Hbuf[wr * 64 + rt * 16 + lr][kc * 32 + lg * 8];
#pragma unroll
    for (int ct = 0; ct < 4; ++ct) {
      bh2[ct] = *(const bf16x8*)&Bhi[wcc * 64 + ct * 16 + lr][lg * 8];
      bl2[ct] = *(const bf16x8*)&Blo[wcc * 64 + ct * 16 + lr][lg * 8];
    }
#pragma unroll
    for (int rt = 0; rt < 4; ++rt)
#pragma unroll
      for (int ct = 0; ct < 4; ++ct) {
        acc2[rt][ct] = __builtin_amdgcn_mfma_f32_16x16x32_bf16(av2[rt], bl2[ct], acc2[rt][ct], 0, 0, 0);
        acc2[rt][ct] = __builtin_amdgcn_mfma_f32_16x16x32_bf16(av2[rt], bh2[ct], acc2[rt][ct], 0, 0, 0);
      }
  }

  // ---------------- f32 epilogue: b2 + LN stats from registers ----------------
  // fragment mapping: row rr = wr*64 + rt*16 + lg*4 + q ; col cc = wcc*64 + ct*16 + lr
  float s1[4][4], s2[4][4];
#pragma unroll
  for (int rt = 0; rt < 4; ++rt)
#pragma unroll
    for (int q = 0; q < 4; ++q) { s1[rt][q] = 0.f; s2[rt][q] = 0.f; }
#pragma unroll
  for (int rt = 0; rt < 4; ++rt)
#pragma unroll
    for (int ct = 0; ct < 4; ++ct) {
      const float bb = b2s[wcc * 64 + ct * 16 + lr];
#pragma unroll
      for (int q = 0; q < 4; ++q) {
        float v = acc2[rt][ct][q] + bb;
        acc2[rt][ct][q] = v;
        s1[rt][q] += v;
        s2[rt][q] += v * v;
      }
    }
  // reduce over the 16 lr-lanes (masks stay within 16-lane groups)
#pragma unroll
  for (int m = 1; m < 16; m <<= 1) {
#pragma unroll
    for (int rt = 0; rt < 4; ++rt)
#pragma unroll
      for (int q = 0; q < 4; ++q) {
        s1[rt][q] += __shfl_xor(s1[rt][q], m);
        s2[rt][q] += __shfl_xor(s2[rt][q], m);
      }
  }
  __syncthreads();   // protect sumL/sqL (fresh) + everyone past phase-2 LDS reads
  {
    // lane lr writes row (rt = lr>>2, q = lr&3) of its lg-group
    const int rt = lr >> 2, q = lr & 3;
    const int rr = wr * 64 + rt * 16 + lg * 4 + q;
    sumL[wcc][rr] = s1[rt][q];
    sqL[wcc][rr]  = s2[rt][q];
  }
  __syncthreads();
  if (t < 128) {
    const float tot = sumL[0][t] + sumL[1][t];
    const float tsq = sqL[0][t] + sqL[1][t];
    const float mu  = tot * (1.0f / 128.0f);
    const float var = tsq * (1.0f / 128.0f) - mu * mu;
    muL[t] = mu;
    rsL[t] = rsqrtf(var + 1e-5f);
  }
  __syncthreads();

  // ---------------- normalize + residual + store + (edge) scatter-add ----------------
#pragma unroll
  for (int rt = 0; rt < 4; ++rt) {
#pragma unroll
    for (int q = 0; q < 4; ++q) {
      const int rr = wr * 64 + rt * 16 + lg * 4 + q;
      const int grow = row0 + rr;
      if (grow < P.nRows) {
        const float mu = muL[rr], rs = rsL[rr];
        const float* rin = P.attrIn + (size_t)grow * LDIM;
        float* rout = P.attrOut + (size_t)grow * LDIM;
        float* ssum = nullptr;
        if (IS_EDGE) ssum = P.sum1 + (size_t)idxb[rr] * LDIM;
#pragma unroll
        for (int ct = 0; ct < 4; ++ct) {
          const int cc = wcc * 64 + ct * 16 + lr;
          const float o = gs[cc] * (acc2[rt][ct][q] - mu) * rs + bes[cc] + rin[cc];
          rout[cc] = o;
          if (IS_EDGE) atomicAdd(ssum + cc, o);
        }
      }
    }
  }
}

// ---- prep kernels ----
__global__ void prep_weights(const float* w1a, const float* w1b, const float* w1c,
                             const float* w2a, const float* w2b, const float* w2c,
                             short* w1h, short* w1l, short* w2h, short* w2l) {
  int i = blockIdx.x * 256 + threadIdx.x;
  constexpr int N1 = 18 * 128 * 384;
  constexpr int N2 = 18 * 128 * 128;
  if (i < N1) {
    int g = i / (128 * 384);
    int rem = i - g * (128 * 384);
    int n = rem / 384, k = rem - n * 384;
    int m = g / 6, s = g - m * 6;
    const float* src = (m == 0) ? w1a : (m == 1) ? w1b : w1c;
    float f = src[(size_t)s * (384 * 128) + (size_t)k * 128 + n];
    short hi = f2b(f);
    w1h[i] = hi;
    w1l[i] = f2b(f - b2f(hi));
  } else if (i < N1 + N2) {
    int j = i - N1;
    int g = j / (128 * 128);
    int rem = j - g * (128 * 128);
    int n = rem / 128, k = rem - n * 128;
    int m = g / 6, s = g - m * 6;
    const float* src = (m == 0) ? w2a : (m == 1) ? w2b : w2c;
    float f = src[(size_t)s * (128 * 128) + (size_t)k * 128 + n];
    short hi = f2b(f);
    w2h[j] = hi;
    w2l[j] = f2b(f - b2f(hi));
  }
}

__global__ void prep_deg(const int* mr, const int* wrcv, int* degm, int* degw) {
  int i = blockIdx.x * 256 + threadIdx.x;
  if (i < EM_N) atomicAdd(&degm[mr[i]], 1);
  else if (i < EM_N + EW_N) atomicAdd(&degw[wrcv[i - EM_N]], 1);
}

__global__ void prep_inv(const int* degm, const int* degw, float* invm, float* invw) {
  int i = blockIdx.x * 256 + threadIdx.x;
  if (i < NNODE) {
    invm[i] = 1.0f / fmaxf((float)degm[i], 1.0f);
    invw[i] = 1.0f / fmaxf((float)degw[i], 1.0f);
  }
}

extern "C" void kernel_launch(void* const* d_in, const int* in_sizes, int n_in,
                              void* d_out, int out_size, void* d_ws, size_t ws_size,
                              hipStream_t stream) {
  (void)in_sizes; (void)n_in; (void)out_size; (void)ws_size;
  const float* x_in   = (const float*)d_in[0];
  const float* mea_in = (const float*)d_in[1];
  const float* wea_in = (const float*)d_in[2];
  const int*   mei    = (const int*)d_in[3];
  const int*   wei    = (const int*)d_in[4];
  const float* W1s[3] = { (const float*)d_in[5],  (const float*)d_in[11], (const float*)d_in[17] };
  const float* B1s[3] = { (const float*)d_in[6],  (const float*)d_in[12], (const float*)d_in[18] };
  const float* W2s[3] = { (const float*)d_in[7],  (const float*)d_in[13], (const float*)d_in[19] };
  const float* B2s[3] = { (const float*)d_in[8],  (const float*)d_in[14], (const float*)d_in[20] };
  const float* Gs[3]  = { (const float*)d_in[9],  (const float*)d_in[15], (const float*)d_in[21] };
  const float* Be[3]  = { (const float*)d_in[10], (const float*)d_in[16], (const float*)d_in[22] };

  float* xo  = (float*)d_out;
  float* meo = xo  + (size_t)NNODE * LDIM;
  float* weo = meo + (size_t)EM_N * LDIM;

  float* msum = (float*)d_ws;
  float* wsum = msum + (size_t)NNODE * LDIM;
  int*   degm = (int*)(wsum + (size_t)NNODE * LDIM);
  int*   degw = degm + NNODE;
  float* invm = (float*)(degw + NNODE);
  float* invw = invm + NNODE;
  short* w1h  = (short*)(invw + NNODE);
  short* w1l  = w1h + (size_t)18 * 128 * 384;
  short* w2h  = w1l + (size_t)18 * 128 * 384;
  short* w2l  = w2h + (size_t)18 * 128 * 128;

  // zero sums + degree counters (inv/weights filled by prep kernels)
  size_t zbytes = (size_t)2 * NNODE * LDIM * 4 + (size_t)2 * NNODE * 4;
  hipMemsetAsync(d_ws, 0, zbytes, stream);

  {
    int tot = 18 * 128 * 384 + 18 * 128 * 128;
    prep_weights<<<dim3((tot + 255) / 256), 256, 0, stream>>>(
        W1s[0], W1s[1], W1s[2], W2s[0], W2s[1], W2s[2], w1h, w1l, w2h, w2l);
  }
  prep_deg<<<dim3((EM_N + EW_N + 255) / 256), 256, 0, stream>>>(mei + EM_N, wei + EW_N, degm, degw);
  prep_inv<<<dim3((NNODE + 255) / 256), 256, 0, stream>>>(degm, degw, invm, invw);

  const int MB = (EM_N + 127) / 128;   // 782
  const int WB = (EW_N + 127) / 128;   // 196
  const int NB = (NNODE + 127) / 128;  // 157

  const float* xc = x_in;
  const float* mc = mea_in;
  const float* wc = wea_in;

  for (int s = 0; s < NSTEP; ++s) {
    MlpParams pm{}, pw{}, pn{};

    pm.x = xc; pm.attrIn = mc; pm.attrOut = meo;
    pm.src = mei; pm.dst = mei + EM_N;
    pm.sum1 = msum; pm.sum2 = nullptr; pm.inv1 = nullptr; pm.inv2 = nullptr;
    pm.W1H = w1h + (size_t)(0 * 6 + s) * 128 * 384;
    pm.W1L = w1l + (size_t)(0 * 6 + s) * 128 * 384;
    pm.W2H = w2h + (size_t)(0 * 6 + s) * 128 * 128;
    pm.W2L = w2l + (size_t)(0 * 6 + s) * 128 * 128;
    pm.b1 = B1s[0] + s * LDIM; pm.b2 = B2s[0] + s * LDIM;
    pm.gam = Gs[0] + s * LDIM; pm.bet = Be[0] + s * LDIM;
    pm.nRows = EM_N;

    pw.x = xc; pw.attrIn = wc; pw.attrOut = weo;
    pw.src = wei; pw.dst = wei + EW_N;
    pw.sum1 = wsum; pw.sum2 = nullptr; pw.inv1 = nullptr; pw.inv2 = nullptr;
    pw.W1H = w1h + (size_t)(1 * 6 + s) * 128 * 384;
    pw.W1L = w1l + (size_t)(1 * 6 + s) * 128 * 384;
    pw.W2H = w2h + (size_t)(1 * 6 + s) * 128 * 128;
    pw.W2L = w2l + (size_t)(1 * 6 + s) * 128 * 128;
    pw.b1 = B1s[1] + s * LDIM; pw.b2 = B2s[1] + s * LDIM;
    pw.gam = Gs[1] + s * LDIM; pw.bet = Be[1] + s * LDIM;
    pw.nRows = EW_N;

    mlp_kernel<true><<<dim3(MB + WB), 256, 0, stream>>>(pm, pw, MB);

    pn.x = xc; pn.attrIn = xc; pn.attrOut = xo;
    pn.src = nullptr; pn.dst = nullptr;
    pn.sum1 = msum; pn.sum2 = wsum; pn.inv1 = invm; pn.inv2 = invw;
    pn.W1H = w1h + (size_t)(2 * 6 + s) * 128 * 384;
    pn.W1L = w1l + (size_t)(2 * 6 + s) * 128 * 384;
    pn.W2H = w2h + (size_t)(2 * 6 + s) * 128 * 128;
    pn.W2L = w2l + (size_t)(2 * 6 + s) * 128 * 128;
    pn.b1 = B1s[2] + s * LDIM; pn.b2 = B2s[2] + s * LDIM;
    pn.gam = Gs[2] + s * LDIM; pn.bet = Be[2] + s * LDIM;
    pn.nRows = NNODE;

    mlp_kernel<false><<<dim3(NB), 256, 0, stream>>>(pn, pn, NB);

    xc = xo; mc = meo; wc = weo;
  }
}